// Round 9
// baseline (648.837 us; speedup 1.0000x reference)
//
#include <hip/hip_runtime.h>

typedef unsigned short USH;
typedef unsigned int UIN;
typedef _Float16 F16;
typedef F16 h2 __attribute__((ext_vector_type(2)));
typedef short bfrag __attribute__((ext_vector_type(8)));   // 8 bf16 (4 VGPR)
typedef float f32x4 __attribute__((ext_vector_type(4)));

__device__ __forceinline__ float bf2f(USH u) {
    return __uint_as_float(((unsigned int)u) << 16);
}
__device__ __forceinline__ USH f2bf(float f) {
    unsigned int i = __float_as_uint(f);
    i += 0x7FFFu + ((i >> 16) & 1u);   // RNE; values are finite
    return (USH)(i >> 16);
}
__device__ __forceinline__ UIN pkh2(float a, float b) {   // 2x f32 -> packed f16 (RNE)
    h2 h; h.x = (F16)a; h.y = (F16)b;
    return __builtin_bit_cast(UIN, h);
}
__device__ __forceinline__ h2 u2h(UIN u) { return __builtin_bit_cast(h2, u); }
__device__ __forceinline__ h2 relu2h(h2 s) {
    const h2 zz = {(F16)0.0f, (F16)0.0f};
    return __builtin_elementwise_max(s, zz);
}
__device__ __forceinline__ float fdot2(h2 a, h2 b, float c) {
#if __has_builtin(__builtin_amdgcn_fdot2)
    return __builtin_amdgcn_fdot2(a, b, c, false);
#else
    return c + (float)a.x * (float)b.x + (float)a.y * (float)b.y;
#endif
}

// flag: 1 = global inputs are bf16, 0 = f32
__device__ __forceinline__ float ldf(const void* p, long idx, int bf) {
    return bf ? bf2f(((const USH*)p)[idx]) : ((const float*)p)[idx];
}
__device__ __forceinline__ void ld4(const void* p, long idx, int bf, float o[4]) {
    if (bf) {
        ushort4 u = *(const ushort4*)((const USH*)p + idx);
        o[0] = bf2f(u.x); o[1] = bf2f(u.y); o[2] = bf2f(u.z); o[3] = bf2f(u.w);
    } else {
        float4 v = *(const float4*)((const float*)p + idx);
        o[0] = v.x; o[1] = v.y; o[2] = v.z; o[3] = v.w;
    }
}

// dtype detect from Ind (U(0,1) values). bf16: every ushort < 0x8000.
__device__ __forceinline__ int detect_bf(const void* ind) {
    const uint4* p = (const uint4*)ind;
    unsigned o = 0;
    #pragma unroll
    for (int i = 0; i < 8; ++i) { uint4 v = p[i]; o |= v.x | v.y | v.z | v.w; }
    return (o & 0x8000u) == 0;
}

// ---------------------------------------------------------------------------
// LEDGER (hardware-observed):
//  * per-t global partial writes: 76x HBM read amplification (banned).
//  * wave-uniform GLOBAL inner-loop operands: waitcnt serialization (banned).
//  * phantom WRITE_SIZE >> 16 MB == scratch spill. Guard: WRITE ~= 16 MB.
//  * R6/R7: tile shrink & barrier-free 1-wave blocks both ~= R5 (60-61 us);
//    k_main is issue-mix-limited, not sync-structure-limited.
//  * R8: MFMA-from-E epilogue = latency-exposed tail, 60->78 us (reverted).
//    Late-kernel latency chains are unhidable; keep Dm precompute+stream.
//  * Residue (total - k_main) ~= 100 us, mostly harness-fixed.
// R9 = R5 (proven best, 162.2 total / 61 k_main) with ONE axis changed:
// Section A stages+computes TWO planes per barrier round (barriers 8 -> 4+1,
// LDS 18 -> 33 KB, still 4 blocks/CU). Everything else byte-identical to R5.
// PROVEN-CORRECT: MFMA D-part (R3/R4/R5; D symmetric => transpose-safe).
// ---------------------------------------------------------------------------

// ---------------------------------------------------------------------------
// Kernel 1: blocks [0,512): D[k] = E_k E_k^T via mfma_f32_16x16x32_bf16,
// 128x128 tiles, XOR-swizzled LDS. blocks [512,800): h-buffers (f16 pairs,
// [9][32 cp][1024 row], plane 8 = W1s/section-B tile). IDENTICAL to R5.
// ---------------------------------------------------------------------------
__global__ __launch_bounds__(256) void k_pre_d(
    const void* __restrict__ x,    // [1024][8][64]
    const void* __restrict__ W1m,  // [128][64]
    const void* __restrict__ b1m,  // [64]
    const void* __restrict__ W1s,  // [128][64]
    const void* __restrict__ b1s,  // [64]
    const void* __restrict__ E,    // [8][1024][64]
    const void* __restrict__ IndDet,
    UIN* __restrict__ hA16,        // [9][32][1024] f16x2
    UIN* __restrict__ hB16,        // [9][32][1024] f16x2
    USH* __restrict__ D)           // [8][1024][1024] bf16
{
    __shared__ float smem[8192];   // 32 KB
    const int bf = detect_bf(IndDet);
    const int tid = threadIdx.x;
    const int bid = blockIdx.x;

    if (bid < 512) {
        // ---- D part: MFMA (verified R3/R4/R5) ----
        USH* sE = (USH*)smem;                  // [2][128 row][64 c] swizzled
        const int k = bid >> 6;
        const int nb = ((bid >> 3) & 7) * 128, mb = (bid & 7) * 128;
        const long ek = (long)k * 65536;

        const int row = tid >> 1;
        const int c0 = (tid & 1) * 32;
        #pragma unroll
        for (int side = 0; side < 2; ++side) {
            const int rbase = side ? mb : nb;
            USH* sDst = sE + side * 8192;
            const long gbase = ek + (long)(rbase + row) * 64 + c0;
            USH tmp[32];
            if (bf) {
                #pragma unroll
                for (int q = 0; q < 4; ++q)
                    *(uint4*)&tmp[q * 8] = *(const uint4*)((const USH*)E + gbase + q * 8);
            } else {
                #pragma unroll
                for (int q = 0; q < 4; ++q) {
                    const float4 va = *(const float4*)((const float*)E + gbase + q * 8);
                    const float4 vb = *(const float4*)((const float*)E + gbase + q * 8 + 4);
                    tmp[q * 8 + 0] = f2bf(va.x); tmp[q * 8 + 1] = f2bf(va.y);
                    tmp[q * 8 + 2] = f2bf(va.z); tmp[q * 8 + 3] = f2bf(va.w);
                    tmp[q * 8 + 4] = f2bf(vb.x); tmp[q * 8 + 5] = f2bf(vb.y);
                    tmp[q * 8 + 6] = f2bf(vb.z); tmp[q * 8 + 7] = f2bf(vb.w);
                }
            }
            #pragma unroll
            for (int q = 0; q < 4; ++q) {
                const int byte = (c0 + q * 8) * 2;
                const int sw = (row * 128 + (byte ^ ((row & 7) << 4))) >> 1;
                *(uint4*)&sDst[sw] = *(uint4*)&tmp[q * 8];
            }
        }
        __syncthreads();

        const int lane = tid & 63;
        const int w = tid >> 6;
        const int wn = (w >> 1) * 64, wm = (w & 1) * 64;
        const int fr = lane & 15, kg = lane >> 4;

        f32x4 acc[4][4] = {};
        #pragma unroll
        for (int ks = 0; ks < 2; ++ks) {
            const int cb = (ks * 32 + kg * 8) * 2;   // byte offset of 8 bf16
            bfrag af[4], bfv[4];
            #pragma unroll
            for (int f = 0; f < 4; ++f) {
                const int ra = wn + f * 16 + fr;
                af[f] = *(const bfrag*)&sE[(ra * 128 + (cb ^ ((ra & 7) << 4))) >> 1];
                const int rb = wm + f * 16 + fr;
                bfv[f] = *(const bfrag*)&sE[8192 + ((rb * 128 + (cb ^ ((rb & 7) << 4))) >> 1)];
            }
            #pragma unroll
            for (int fn = 0; fn < 4; ++fn)
                #pragma unroll
                for (int fm = 0; fm < 4; ++fm)
                    acc[fn][fm] = __builtin_amdgcn_mfma_f32_16x16x32_bf16(
                        af[fn], bfv[fm], acc[fn][fm], 0, 0, 0);
        }

        USH* Dk = D + ((long)k << 20);
        #pragma unroll
        for (int fn = 0; fn < 4; ++fn) {
            const int nrow = nb + wn + fn * 16 + kg * 4;
            #pragma unroll
            for (int fm = 0; fm < 4; ++fm) {
                const int mcol = mb + wm + fm * 16 + fr;
                #pragma unroll
                for (int r = 0; r < 4; ++r)
                    Dk[(long)(nrow + r) * 1024 + mcol] = f2bf(acc[fn][fm][r]);
            }
        }
    } else {
        // ---- precompute part: h = x_t @ W1 (+bias on B-side), f16-pair out ----
        float* sA = smem;          // 4096
        float* sB = smem + 4096;   // 4096
        const int tx = tid & 15, ty = tid >> 4;
        const int bid2 = bid - 512;
        const int nbase = (bid2 & 15) * 64;
        const int by = bid2 >> 4;   // 0..17
        int t, rb;
        const void* Wsrc;
        const void* bias;
        UIN* dst;
        if (by < 8)        { t = by;     rb = 0;  Wsrc = W1m; bias = nullptr; dst = hA16 + by * 32768; }
        else if (by < 16)  { t = by - 8; rb = 64; Wsrc = W1m; bias = b1m;     dst = hB16 + (by - 8) * 32768; }
        else if (by == 16) { t = 7;      rb = 0;  Wsrc = W1s; bias = nullptr; dst = hA16 + 8 * 32768; }
        else               { t = 7;      rb = 64; Wsrc = W1s; bias = b1s;     dst = hB16 + 8 * 32768; }

        {   // stage x tile -> sA[d][n] (transpose on LDS write)
            const int n_l = tid >> 2, dq = tid & 3;
            const long base = (long)(nbase + n_l) * 512 + t * 64 + dq * 16;
            #pragma unroll
            for (int j = 0; j < 4; ++j) {
                float o[4]; ld4(x, base + j * 4, bf, o);
                const int d0 = dq * 16 + j * 4;
                #pragma unroll
                for (int e = 0; e < 4; ++e) sA[(d0 + e) * 64 + n_l] = o[e];
            }
        }
        {   // stage W tile -> sB[d][c]
            const int d_l = tid >> 2, cq = tid & 3;
            const long base = (long)(rb + d_l) * 64 + cq * 16;
            #pragma unroll
            for (int j = 0; j < 4; ++j) {
                float o[4]; ld4(Wsrc, base + j * 4, bf, o);
                const int c0 = cq * 16 + j * 4;
                #pragma unroll
                for (int e = 0; e < 4; ++e) sB[d_l * 64 + c0 + e] = o[e];
            }
        }
        __syncthreads();

        const int c0 = tx * 4, nq = ty * 4;
        float acc[4][4] = {};  // [ci][ni]
        #pragma unroll 16
        for (int d = 0; d < 64; ++d) {
            const float4 xa = *(const float4*)&sA[d * 64 + nq];
            const float4 wv = *(const float4*)&sB[d * 64 + c0];
            const float aa[4] = {xa.x, xa.y, xa.z, xa.w};
            const float ww[4] = {wv.x, wv.y, wv.z, wv.w};
            #pragma unroll
            for (int ci = 0; ci < 4; ++ci)
                #pragma unroll
                for (int ni = 0; ni < 4; ++ni)
                    acc[ci][ni] += ww[ci] * aa[ni];
        }
        float b[4] = {0.f, 0.f, 0.f, 0.f};
        if (bias) {
            #pragma unroll
            for (int ci = 0; ci < 4; ++ci) b[ci] = ldf(bias, c0 + ci, bf);
        }
        const int cp0 = c0 >> 1;   // even
        #pragma unroll
        for (int ni = 0; ni < 4; ++ni) {
            const int col = nbase + nq + ni;
            dst[cp0 * 1024 + col]       = pkh2(acc[0][ni] + b[0], acc[1][ni] + b[1]);
            dst[(cp0 + 1) * 1024 + col] = pkh2(acc[2][ni] + b[2], acc[3][ni] + b[3]);
        }
    }
}

// ---------------------------------------------------------------------------
// Kernel 2: R5 skeleton; ONE axis changed: 2 planes per barrier round.
// Tile 32n x 32m, 256 threads, per-thread 2n x 2m, f16 c-pair LDS.
// Buffers hold 2 planes each; barriers 8 -> 5 total in Section A.
// ---------------------------------------------------------------------------
__global__ __launch_bounds__(256, 4) void k_main(
    const UIN* __restrict__ hA16,   // [9][32][1024]
    const UIN* __restrict__ hB16,   // [9][32][1024]
    const USH* __restrict__ Dm,     // [8][1024][1024] bf16
    const void* __restrict__ Ind, const void* __restrict__ Loc,
    const void* __restrict__ a, const void* __restrict__ W2m,
    const void* __restrict__ b2m, const void* __restrict__ W2s,
    const void* __restrict__ b2s, const void* __restrict__ g,
    void* __restrict__ out)
{
    __shared__ UIN As[2 * 2048];  // [buf][plane][32 cp][32 n], 16 KB
    __shared__ UIN Bs[2 * 2048];  // [buf][plane][32 cp][32 m], 16 KB
    __shared__ UIN w2m16[32];     // [cp] f16x2
    __shared__ UIN w2s16[256];    // [cp][k] f16x2 (pair over c)
    __shared__ float asoft_l[8];

    const int bf = detect_bf(Ind);
    const int tid = threadIdx.x;
    const int mb = blockIdx.x * 32, nb = blockIdx.y * 32;
    const int tx = tid & 15, ty = tid >> 4;
    const int m0 = tx * 2, n0 = ty * 2;

    // -- weight staging (small; scalar loads fine) --
    if (tid < 32) w2m16[tid] = pkh2(ldf(W2m, 2 * tid, bf), ldf(W2m, 2 * tid + 1, bf));
    if (tid >= 64 && tid < 96) {
        const int cp = tid - 64;
        #pragma unroll
        for (int k = 0; k < 8; ++k)
            w2s16[cp * 8 + k] = pkh2(ldf(W2s, (2 * cp) * 8 + k, bf),
                                     ldf(W2s, (2 * cp + 1) * 8 + k, bf));
    }
    if (tid < 8) {
        float av[8], mx = -1e30f, s = 0.0f;
        #pragma unroll
        for (int k = 0; k < 8; ++k) { av[k] = ldf(a, k, bf); mx = fmaxf(mx, av[k]); }
        #pragma unroll
        for (int k = 0; k < 8; ++k) s += __expf(av[k] - mx);
        asoft_l[tid] = __expf(av[tid] - mx) / s;
    }
    const float b2m_f = ldf(b2m, 0, bf);

    // -- staging addresses: 32 cp rows x 32 u32 cols; uint4 per thread --
    const int offA = (tid >> 3) * 1024 + nb + (tid & 7) * 4;   // u32 idx in plane
    const int offB = (tid >> 3) * 1024 + mb + (tid & 7) * 4;
    const int ldsOff = (tid >> 3) * 32 + (tid & 7) * 4;        // u32 idx in tile

    // -- initial stage: planes 0,1 into buffer 0 --
    {
        const uint4 a0 = *(const uint4*)(hA16 + offA);
        const uint4 a1 = *(const uint4*)(hA16 + 32768 + offA);
        const uint4 b0 = *(const uint4*)(hB16 + offB);
        const uint4 b1 = *(const uint4*)(hB16 + 32768 + offB);
        *(uint4*)&As[ldsOff] = a0;        *(uint4*)&As[1024 + ldsOff] = a1;
        *(uint4*)&Bs[ldsOff] = b0;        *(uint4*)&Bs[1024 + ldsOff] = b1;
    }
    __syncthreads();

    float amk[2][2] = {{0.f, 0.f}, {0.f, 0.f}};   // [n][m]

    // ---- Section A: 8 time steps, 2 planes per barrier round ----
    for (int it = 0; it < 4; ++it) {
        const int cur = it & 1, nxt = cur ^ 1;
        // prefetch planes 2it+2, 2it+3 (it=3: plane 8 = section-B tile, once)
        const int p0 = 2 * it + 2;
        const uint4 pa0 = *(const uint4*)(hA16 + p0 * 32768 + offA);
        const uint4 pb0 = *(const uint4*)(hB16 + p0 * 32768 + offB);
        uint4 pa1, pb1;
        if (it < 3) {
            pa1 = *(const uint4*)(hA16 + (p0 + 1) * 32768 + offA);
            pb1 = *(const uint4*)(hB16 + (p0 + 1) * 32768 + offB);
        }

        #pragma unroll
        for (int pl = 0; pl < 2; ++pl) {
            const int t = 2 * it + pl;
            const UIN* Ac = &As[cur * 2048 + pl * 1024];
            const UIN* Bc = &Bs[cur * 2048 + pl * 1024];
            float a00 = 0.f, a01 = 0.f, a10 = 0.f, a11 = 0.f;
            #pragma unroll
            for (int cp = 0; cp < 32; ++cp) {
                const uint2 au = *(const uint2*)&Ac[(cp << 5) + n0];
                const uint2 bu = *(const uint2*)&Bc[(cp << 5) + m0];
                const h2 wv = u2h(w2m16[cp]);
                const h2 a0 = u2h(au.x), a1 = u2h(au.y);
                const h2 b0 = u2h(bu.x), b1 = u2h(bu.y);
                const h2 z00 = relu2h(a0 + b0), z01 = relu2h(a0 + b1);
                const h2 z10 = relu2h(a1 + b0), z11 = relu2h(a1 + b1);
                a00 = fdot2(z00, wv, a00); a01 = fdot2(z01, wv, a01);
                a10 = fdot2(z10, wv, a10); a11 = fdot2(z11, wv, a11);
            }
            const float as_t = asoft_l[t];
            amk[0][0] += fmaxf(a00 + b2m_f, 0.f) * as_t;
            amk[0][1] += fmaxf(a01 + b2m_f, 0.f) * as_t;
            amk[1][0] += fmaxf(a10 + b2m_f, 0.f) * as_t;
            amk[1][1] += fmaxf(a11 + b2m_f, 0.f) * as_t;
        }

        // write staged planes to the other buffer, then barrier
        *(uint4*)&As[nxt * 2048 + ldsOff] = pa0;
        *(uint4*)&Bs[nxt * 2048 + ldsOff] = pb0;
        if (it < 3) {
            *(uint4*)&As[nxt * 2048 + 1024 + ldsOff] = pa1;
            *(uint4*)&Bs[nxt * 2048 + 1024 + ldsOff] = pb1;
        }
        __syncthreads();
    }

    // ---- Section B: logits (plane 8 in buffer 0, slot 0) ----
    float lg[2][2][8];   // [n][m][k]
    #pragma unroll
    for (int i = 0; i < 2; ++i)
        #pragma unroll
        for (int j = 0; j < 2; ++j)
            #pragma unroll
            for (int k = 0; k < 8; ++k) lg[i][j][k] = 0.f;

    #pragma unroll 8
    for (int cp = 0; cp < 32; ++cp) {
        const uint2 au = *(const uint2*)&As[(cp << 5) + n0];
        const uint2 bu = *(const uint2*)&Bs[(cp << 5) + m0];
        const h2 a0 = u2h(au.x), a1 = u2h(au.y);
        const h2 b0 = u2h(bu.x), b1 = u2h(bu.y);
        const h2 z00 = relu2h(a0 + b0), z01 = relu2h(a0 + b1);
        const h2 z10 = relu2h(a1 + b0), z11 = relu2h(a1 + b1);
        const uint4 wa = *(const uint4*)&w2s16[cp * 8];
        const uint4 wb = *(const uint4*)&w2s16[cp * 8 + 4];
        const UIN wks[8] = {wa.x, wa.y, wa.z, wa.w, wb.x, wb.y, wb.z, wb.w};
        #pragma unroll
        for (int k = 0; k < 8; ++k) {
            const h2 wv = u2h(wks[k]);
            lg[0][0][k] = fdot2(z00, wv, lg[0][0][k]);
            lg[0][1][k] = fdot2(z01, wv, lg[0][1][k]);
            lg[1][0][k] = fdot2(z10, wv, lg[1][0][k]);
            lg[1][1][k] = fdot2(z11, wv, lg[1][1][k]);
        }
    }

    // ---- Epilogue: softmax(relu(lg+b2s)+g) . D  (identical to R5) ----
    float b2s_f[8];
    #pragma unroll
    for (int k = 0; k < 8; ++k) b2s_f[k] = ldf(b2s, k, bf);

    #pragma unroll
    for (int i = 0; i < 2; ++i) {
        const long rowoff = (long)(nb + n0 + i) * 1024 + mb + m0;
        float gv[16];
        ld4(g, rowoff * 8 + 0, bf, gv + 0);
        ld4(g, rowoff * 8 + 4, bf, gv + 4);
        ld4(g, rowoff * 8 + 8, bf, gv + 8);
        ld4(g, rowoff * 8 + 12, bf, gv + 12);

        float s0 = 0.0f, s1 = 0.0f, d0 = 0.0f, d1 = 0.0f;
        #pragma unroll
        for (int k = 0; k < 8; ++k) {
            const float l0 = fmaxf(lg[i][0][k] + b2s_f[k], 0.f);
            const float l1 = fmaxf(lg[i][1][k] + b2s_f[k], 0.f);
            const float e0 = __expf(l0 + gv[k]);
            const float e1 = __expf(l1 + gv[8 + k]);
            s0 += e0; s1 += e1;
            const ushort2 dv = *(const ushort2*)&Dm[((long)k << 20) + rowoff];
            d0 += bf2f(dv.x) * e0;
            d1 += bf2f(dv.y) * e1;
        }

        if (bf) {
            USH* o = (USH*)out;
            *(ushort2*)&o[rowoff] = *(const ushort2*)&((const USH*)Ind)[rowoff];
            *(ushort2*)&o[1048576 + rowoff] = *(const ushort2*)&((const USH*)Loc)[rowoff];
            ushort2 o2; o2.x = f2bf(amk[i][0]); o2.y = f2bf(amk[i][1]);
            *(ushort2*)&o[2 * 1048576 + rowoff] = o2;
            ushort2 o3; o3.x = f2bf(d0 / s0); o3.y = f2bf(d1 / s1);
            *(ushort2*)&o[3 * 1048576 + rowoff] = o3;
        } else {
            float* o = (float*)out;
            *(float2*)&o[rowoff] = *(const float2*)&((const float*)Ind)[rowoff];
            *(float2*)&o[1048576 + rowoff] = *(const float2*)&((const float*)Loc)[rowoff];
            float2 o2; o2.x = amk[i][0]; o2.y = amk[i][1];
            *(float2*)&o[2 * 1048576 + rowoff] = o2;
            float2 o3; o3.x = d0 / s0; o3.y = d1 / s1;
            *(float2*)&o[3 * 1048576 + rowoff] = o3;
        }
    }
}

extern "C" void kernel_launch(void* const* d_in, const int* in_sizes, int n_in,
                              void* d_out, int out_size, void* d_ws, size_t ws_size,
                              hipStream_t stream) {
    const void* x   = d_in[0];
    const void* Ind = d_in[1];
    const void* Loc = d_in[2];
    const void* a   = d_in[3];
    const void* W1m = d_in[4];
    const void* b1m = d_in[5];
    const void* W2m = d_in[6];
    const void* b2m = d_in[7];
    const void* W1s = d_in[8];
    const void* b1s = d_in[9];
    const void* W2s = d_in[10];
    const void* b2s = d_in[11];
    const void* E   = d_in[12];
    const void* g   = d_in[13];

    UIN* ws   = (UIN*)d_ws;
    UIN* hA16 = ws;                    // [9][32][1024] u32, 1.125 MB
    UIN* hB16 = hA16 + 294912;         // 1.125 MB
    USH* Dm   = (USH*)(hB16 + 294912); // [8][1024][1024] bf16, 16 MB

    k_pre_d<<<dim3(800), 256, 0, stream>>>(x, W1m, b1m, W1s, b1s, E, Ind,
                                           hA16, hB16, Dm);
    k_main<<<dim3(32, 32), 256, 0, stream>>>(hA16, hB16, Dm,
                                             Ind, Loc, a, W2m, b2m, W2s, b2s,
                                             g, d_out);
}

// Round 10
// 162.430 us; speedup vs baseline: 3.9946x; 3.9946x over previous
//
#include <hip/hip_runtime.h>

typedef unsigned short USH;
typedef unsigned int UIN;
typedef _Float16 F16;
typedef F16 h2 __attribute__((ext_vector_type(2)));
typedef short bfrag __attribute__((ext_vector_type(8)));   // 8 bf16 (4 VGPR)
typedef float f32x4 __attribute__((ext_vector_type(4)));

__device__ __forceinline__ float bf2f(USH u) {
    return __uint_as_float(((unsigned int)u) << 16);
}
__device__ __forceinline__ USH f2bf(float f) {
    unsigned int i = __float_as_uint(f);
    i += 0x7FFFu + ((i >> 16) & 1u);   // RNE; values are finite
    return (USH)(i >> 16);
}
__device__ __forceinline__ UIN pkh2(float a, float b) {   // 2x f32 -> packed f16 (RNE)
    h2 h; h.x = (F16)a; h.y = (F16)b;
    return __builtin_bit_cast(UIN, h);
}
__device__ __forceinline__ h2 u2h(UIN u) { return __builtin_bit_cast(h2, u); }
__device__ __forceinline__ h2 relu2h(h2 s) {
    const h2 zz = {(F16)0.0f, (F16)0.0f};
    return __builtin_elementwise_max(s, zz);
}
__device__ __forceinline__ float fdot2(h2 a, h2 b, float c) {
#if __has_builtin(__builtin_amdgcn_fdot2)
    return __builtin_amdgcn_fdot2(a, b, c, false);
#else
    return c + (float)a.x * (float)b.x + (float)a.y * (float)b.y;
#endif
}

// flag: 1 = global inputs are bf16, 0 = f32
__device__ __forceinline__ float ldf(const void* p, long idx, int bf) {
    return bf ? bf2f(((const USH*)p)[idx]) : ((const float*)p)[idx];
}
__device__ __forceinline__ void ld4(const void* p, long idx, int bf, float o[4]) {
    if (bf) {
        ushort4 u = *(const ushort4*)((const USH*)p + idx);
        o[0] = bf2f(u.x); o[1] = bf2f(u.y); o[2] = bf2f(u.z); o[3] = bf2f(u.w);
    } else {
        float4 v = *(const float4*)((const float*)p + idx);
        o[0] = v.x; o[1] = v.y; o[2] = v.z; o[3] = v.w;
    }
}

// dtype detect from Ind (U(0,1) values). bf16: every ushort < 0x8000.
__device__ __forceinline__ int detect_bf(const void* ind) {
    const uint4* p = (const uint4*)ind;
    unsigned o = 0;
    #pragma unroll
    for (int i = 0; i < 8; ++i) { uint4 v = p[i]; o |= v.x | v.y | v.z | v.w; }
    return (o & 0x8000u) == 0;
}

// ---------------------------------------------------------------------------
// LEDGER (hardware-observed):
//  * per-t global partial writes: 76x HBM read amplification (banned).
//  * wave-uniform GLOBAL inner-loop operands: waitcnt serialization (banned).
//  * phantom WRITE_SIZE >> 16 MB == scratch spill. Guard: WRITE ~= 16 MB.
//    Reported VGPR does NOT show it (R9: VGPR=64, WRITE=1084 MB).
//  * R9: CONDITIONALLY-assigned prefetch registers held across a barrier ->
//    scratch (553 us). Prefetch must be unconditional, straight-line (banned).
//  * R6/R7: tile shrink & barrier-free 1-wave blocks ~= R5 (60-61 us);
//    k_main is issue-mix-limited, not sync-structure-limited.
//  * R8: MFMA-from-E epilogue = latency-exposed tail, 60->78 us (reverted).
//  * Residue (total - k_main) ~= 100 us, mostly harness-fixed.
// R10 = byte-for-byte revert to R5, the proven optimum:
//   total 162.2 us / k_main 61 us / FETCH 42 MB / WRITE 16.4 MB / conf 57K.
// PROVEN-CORRECT: MFMA D-part (R3/R4/R5; D symmetric => transpose-safe).
// ---------------------------------------------------------------------------

// ---------------------------------------------------------------------------
// Kernel 1: blocks [0,512): D[k] = E_k E_k^T via mfma_f32_16x16x32_bf16,
// 128x128 tiles, XOR-swizzled LDS. blocks [512,800): h-buffers (f16 pairs,
// [9][32 cp][1024 row], plane 8 = W1s/section-B tile).
// ---------------------------------------------------------------------------
__global__ __launch_bounds__(256) void k_pre_d(
    const void* __restrict__ x,    // [1024][8][64]
    const void* __restrict__ W1m,  // [128][64]
    const void* __restrict__ b1m,  // [64]
    const void* __restrict__ W1s,  // [128][64]
    const void* __restrict__ b1s,  // [64]
    const void* __restrict__ E,    // [8][1024][64]
    const void* __restrict__ IndDet,
    UIN* __restrict__ hA16,        // [9][32][1024] f16x2
    UIN* __restrict__ hB16,        // [9][32][1024] f16x2
    USH* __restrict__ D)           // [8][1024][1024] bf16
{
    __shared__ float smem[8192];   // 32 KB
    const int bf = detect_bf(IndDet);
    const int tid = threadIdx.x;
    const int bid = blockIdx.x;

    if (bid < 512) {
        // ---- D part: MFMA (verified R3/R4/R5) ----
        USH* sE = (USH*)smem;                  // [2][128 row][64 c] swizzled
        const int k = bid >> 6;
        const int nb = ((bid >> 3) & 7) * 128, mb = (bid & 7) * 128;
        const long ek = (long)k * 65536;

        const int row = tid >> 1;
        const int c0 = (tid & 1) * 32;
        #pragma unroll
        for (int side = 0; side < 2; ++side) {
            const int rbase = side ? mb : nb;
            USH* sDst = sE + side * 8192;
            const long gbase = ek + (long)(rbase + row) * 64 + c0;
            USH tmp[32];
            if (bf) {
                #pragma unroll
                for (int q = 0; q < 4; ++q)
                    *(uint4*)&tmp[q * 8] = *(const uint4*)((const USH*)E + gbase + q * 8);
            } else {
                #pragma unroll
                for (int q = 0; q < 4; ++q) {
                    const float4 va = *(const float4*)((const float*)E + gbase + q * 8);
                    const float4 vb = *(const float4*)((const float*)E + gbase + q * 8 + 4);
                    tmp[q * 8 + 0] = f2bf(va.x); tmp[q * 8 + 1] = f2bf(va.y);
                    tmp[q * 8 + 2] = f2bf(va.z); tmp[q * 8 + 3] = f2bf(va.w);
                    tmp[q * 8 + 4] = f2bf(vb.x); tmp[q * 8 + 5] = f2bf(vb.y);
                    tmp[q * 8 + 6] = f2bf(vb.z); tmp[q * 8 + 7] = f2bf(vb.w);
                }
            }
            #pragma unroll
            for (int q = 0; q < 4; ++q) {
                const int byte = (c0 + q * 8) * 2;
                const int sw = (row * 128 + (byte ^ ((row & 7) << 4))) >> 1;
                *(uint4*)&sDst[sw] = *(uint4*)&tmp[q * 8];
            }
        }
        __syncthreads();

        const int lane = tid & 63;
        const int w = tid >> 6;
        const int wn = (w >> 1) * 64, wm = (w & 1) * 64;
        const int fr = lane & 15, kg = lane >> 4;

        f32x4 acc[4][4] = {};
        #pragma unroll
        for (int ks = 0; ks < 2; ++ks) {
            const int cb = (ks * 32 + kg * 8) * 2;   // byte offset of 8 bf16
            bfrag af[4], bfv[4];
            #pragma unroll
            for (int f = 0; f < 4; ++f) {
                const int ra = wn + f * 16 + fr;
                af[f] = *(const bfrag*)&sE[(ra * 128 + (cb ^ ((ra & 7) << 4))) >> 1];
                const int rb = wm + f * 16 + fr;
                bfv[f] = *(const bfrag*)&sE[8192 + ((rb * 128 + (cb ^ ((rb & 7) << 4))) >> 1)];
            }
            #pragma unroll
            for (int fn = 0; fn < 4; ++fn)
                #pragma unroll
                for (int fm = 0; fm < 4; ++fm)
                    acc[fn][fm] = __builtin_amdgcn_mfma_f32_16x16x32_bf16(
                        af[fn], bfv[fm], acc[fn][fm], 0, 0, 0);
        }

        USH* Dk = D + ((long)k << 20);
        #pragma unroll
        for (int fn = 0; fn < 4; ++fn) {
            const int nrow = nb + wn + fn * 16 + kg * 4;
            #pragma unroll
            for (int fm = 0; fm < 4; ++fm) {
                const int mcol = mb + wm + fm * 16 + fr;
                #pragma unroll
                for (int r = 0; r < 4; ++r)
                    Dk[(long)(nrow + r) * 1024 + mcol] = f2bf(acc[fn][fm][r]);
            }
        }
    } else {
        // ---- precompute part: h = x_t @ W1 (+bias on B-side), f16-pair out ----
        float* sA = smem;          // 4096
        float* sB = smem + 4096;   // 4096
        const int tx = tid & 15, ty = tid >> 4;
        const int bid2 = bid - 512;
        const int nbase = (bid2 & 15) * 64;
        const int by = bid2 >> 4;   // 0..17
        int t, rb;
        const void* Wsrc;
        const void* bias;
        UIN* dst;
        if (by < 8)        { t = by;     rb = 0;  Wsrc = W1m; bias = nullptr; dst = hA16 + by * 32768; }
        else if (by < 16)  { t = by - 8; rb = 64; Wsrc = W1m; bias = b1m;     dst = hB16 + (by - 8) * 32768; }
        else if (by == 16) { t = 7;      rb = 0;  Wsrc = W1s; bias = nullptr; dst = hA16 + 8 * 32768; }
        else               { t = 7;      rb = 64; Wsrc = W1s; bias = b1s;     dst = hB16 + 8 * 32768; }

        {   // stage x tile -> sA[d][n] (transpose on LDS write)
            const int n_l = tid >> 2, dq = tid & 3;
            const long base = (long)(nbase + n_l) * 512 + t * 64 + dq * 16;
            #pragma unroll
            for (int j = 0; j < 4; ++j) {
                float o[4]; ld4(x, base + j * 4, bf, o);
                const int d0 = dq * 16 + j * 4;
                #pragma unroll
                for (int e = 0; e < 4; ++e) sA[(d0 + e) * 64 + n_l] = o[e];
            }
        }
        {   // stage W tile -> sB[d][c]
            const int d_l = tid >> 2, cq = tid & 3;
            const long base = (long)(rb + d_l) * 64 + cq * 16;
            #pragma unroll
            for (int j = 0; j < 4; ++j) {
                float o[4]; ld4(Wsrc, base + j * 4, bf, o);
                const int c0 = cq * 16 + j * 4;
                #pragma unroll
                for (int e = 0; e < 4; ++e) sB[d_l * 64 + c0 + e] = o[e];
            }
        }
        __syncthreads();

        const int c0 = tx * 4, nq = ty * 4;
        float acc[4][4] = {};  // [ci][ni]
        #pragma unroll 16
        for (int d = 0; d < 64; ++d) {
            const float4 xa = *(const float4*)&sA[d * 64 + nq];
            const float4 wv = *(const float4*)&sB[d * 64 + c0];
            const float aa[4] = {xa.x, xa.y, xa.z, xa.w};
            const float ww[4] = {wv.x, wv.y, wv.z, wv.w};
            #pragma unroll
            for (int ci = 0; ci < 4; ++ci)
                #pragma unroll
                for (int ni = 0; ni < 4; ++ni)
                    acc[ci][ni] += ww[ci] * aa[ni];
        }
        float b[4] = {0.f, 0.f, 0.f, 0.f};
        if (bias) {
            #pragma unroll
            for (int ci = 0; ci < 4; ++ci) b[ci] = ldf(bias, c0 + ci, bf);
        }
        const int cp0 = c0 >> 1;   // even
        #pragma unroll
        for (int ni = 0; ni < 4; ++ni) {
            const int col = nbase + nq + ni;
            dst[cp0 * 1024 + col]       = pkh2(acc[0][ni] + b[0], acc[1][ni] + b[1]);
            dst[(cp0 + 1) * 1024 + col] = pkh2(acc[2][ni] + b[2], acc[3][ni] + b[3]);
        }
    }
}

// ---------------------------------------------------------------------------
// Kernel 2: R5-proven skeleton (byte-for-byte). 32n x 32m tiles, grid (32,32),
// 256 threads (2n x 2m per thread), LDS tiles [32 cp][32 row] u32(f16x2),
// double-buffered across t. Inner op per c-pair: v_pk_add_f16 + v_pk_max_f16
// + v_dot2_f32_f16 (f32 accumulate).
// ---------------------------------------------------------------------------
__global__ __launch_bounds__(256, 4) void k_main(
    const UIN* __restrict__ hA16,   // [9][32][1024]
    const UIN* __restrict__ hB16,   // [9][32][1024]
    const USH* __restrict__ Dm,     // [8][1024][1024] bf16
    const void* __restrict__ Ind, const void* __restrict__ Loc,
    const void* __restrict__ a, const void* __restrict__ W2m,
    const void* __restrict__ b2m, const void* __restrict__ W2s,
    const void* __restrict__ b2s, const void* __restrict__ g,
    void* __restrict__ out)
{
    __shared__ UIN As[2][1024];   // [32 cp][32 n], 4 KB each
    __shared__ UIN Bs[2][1024];   // [32 cp][32 m]
    __shared__ UIN w2m16[32];     // [cp] f16x2
    __shared__ UIN w2s16[256];    // [cp][k] f16x2 (pair over c)
    __shared__ float asoft_l[8];

    const int bf = detect_bf(Ind);
    const int tid = threadIdx.x;
    const int mb = blockIdx.x * 32, nb = blockIdx.y * 32;
    const int tx = tid & 15, ty = tid >> 4;
    const int m0 = tx * 2, n0 = ty * 2;

    // -- weight staging (small; scalar loads fine) --
    if (tid < 32) w2m16[tid] = pkh2(ldf(W2m, 2 * tid, bf), ldf(W2m, 2 * tid + 1, bf));
    if (tid >= 64 && tid < 96) {
        const int cp = tid - 64;
        #pragma unroll
        for (int k = 0; k < 8; ++k)
            w2s16[cp * 8 + k] = pkh2(ldf(W2s, (2 * cp) * 8 + k, bf),
                                     ldf(W2s, (2 * cp + 1) * 8 + k, bf));
    }
    if (tid < 8) {
        float av[8], mx = -1e30f, s = 0.0f;
        #pragma unroll
        for (int k = 0; k < 8; ++k) { av[k] = ldf(a, k, bf); mx = fmaxf(mx, av[k]); }
        #pragma unroll
        for (int k = 0; k < 8; ++k) s += __expf(av[k] - mx);
        asoft_l[tid] = __expf(av[tid] - mx) / s;
    }
    const float b2m_f = ldf(b2m, 0, bf);

    // -- staging addresses: 32 cp rows x 32 u32 cols; uint4 per thread --
    const int offA = (tid >> 3) * 1024 + nb + (tid & 7) * 4;   // u32 idx in plane
    const int offB = (tid >> 3) * 1024 + mb + (tid & 7) * 4;
    const int ldsOff = (tid >> 3) * 32 + (tid & 7) * 4;        // u32 idx in tile

    // -- initial stage: t=0 into buffer 0 (straight u32 copies) --
    {
        const uint4 pa = *(const uint4*)(hA16 + offA);
        const uint4 pb = *(const uint4*)(hB16 + offB);
        *(uint4*)&As[0][ldsOff] = pa;
        *(uint4*)&Bs[0][ldsOff] = pb;
    }
    __syncthreads();

    float amk[2][2] = {{0.f, 0.f}, {0.f, 0.f}};   // [n][m]

    // ---- Section A: A_mkt over 8 time steps (double-buffered) ----
    for (int t = 0; t < 8; ++t) {
        const int cur = t & 1, nxt = cur ^ 1;
        // prefetch t+1 (t=7 stages plane 8 = section-B tile)
        const uint4 pa = *(const uint4*)(hA16 + (t + 1) * 32768 + offA);
        const uint4 pb = *(const uint4*)(hB16 + (t + 1) * 32768 + offB);

        float a00 = 0.f, a01 = 0.f, a10 = 0.f, a11 = 0.f;
        #pragma unroll
        for (int cp = 0; cp < 32; ++cp) {
            const uint2 au = *(const uint2*)&As[cur][(cp << 5) + n0];
            const uint2 bu = *(const uint2*)&Bs[cur][(cp << 5) + m0];
            const h2 wv = u2h(w2m16[cp]);
            const h2 a0 = u2h(au.x), a1 = u2h(au.y);
            const h2 b0 = u2h(bu.x), b1 = u2h(bu.y);
            const h2 z00 = relu2h(a0 + b0), z01 = relu2h(a0 + b1);
            const h2 z10 = relu2h(a1 + b0), z11 = relu2h(a1 + b1);
            a00 = fdot2(z00, wv, a00); a01 = fdot2(z01, wv, a01);
            a10 = fdot2(z10, wv, a10); a11 = fdot2(z11, wv, a11);
        }
        const float as_t = asoft_l[t];
        amk[0][0] += fmaxf(a00 + b2m_f, 0.f) * as_t;
        amk[0][1] += fmaxf(a01 + b2m_f, 0.f) * as_t;
        amk[1][0] += fmaxf(a10 + b2m_f, 0.f) * as_t;
        amk[1][1] += fmaxf(a11 + b2m_f, 0.f) * as_t;

        // write staged tile, then barrier
        *(uint4*)&As[nxt][ldsOff] = pa;
        *(uint4*)&Bs[nxt][ldsOff] = pb;
        __syncthreads();
    }

    // ---- Section B: logits (tile 8 in buffer 0 from t=7 prefetch) ----
    float lg[2][2][8];   // [n][m][k]
    #pragma unroll
    for (int i = 0; i < 2; ++i)
        #pragma unroll
        for (int j = 0; j < 2; ++j)
            #pragma unroll
            for (int k = 0; k < 8; ++k) lg[i][j][k] = 0.f;

    #pragma unroll 8
    for (int cp = 0; cp < 32; ++cp) {
        const uint2 au = *(const uint2*)&As[0][(cp << 5) + n0];
        const uint2 bu = *(const uint2*)&Bs[0][(cp << 5) + m0];
        const h2 a0 = u2h(au.x), a1 = u2h(au.y);
        const h2 b0 = u2h(bu.x), b1 = u2h(bu.y);
        const h2 z00 = relu2h(a0 + b0), z01 = relu2h(a0 + b1);
        const h2 z10 = relu2h(a1 + b0), z11 = relu2h(a1 + b1);
        const uint4 wa = *(const uint4*)&w2s16[cp * 8];
        const uint4 wb = *(const uint4*)&w2s16[cp * 8 + 4];
        const UIN wks[8] = {wa.x, wa.y, wa.z, wa.w, wb.x, wb.y, wb.z, wb.w};
        #pragma unroll
        for (int k = 0; k < 8; ++k) {
            const h2 wv = u2h(wks[k]);
            lg[0][0][k] = fdot2(z00, wv, lg[0][0][k]);
            lg[0][1][k] = fdot2(z01, wv, lg[0][1][k]);
            lg[1][0][k] = fdot2(z10, wv, lg[1][0][k]);
            lg[1][1][k] = fdot2(z11, wv, lg[1][1][k]);
        }
    }

    // ---- Epilogue: softmax(relu(lg+b2s)+g) . D ----
    float b2s_f[8];
    #pragma unroll
    for (int k = 0; k < 8; ++k) b2s_f[k] = ldf(b2s, k, bf);

    #pragma unroll
    for (int i = 0; i < 2; ++i) {
        const long rowoff = (long)(nb + n0 + i) * 1024 + mb + m0;
        float gv[16];
        ld4(g, rowoff * 8 + 0, bf, gv + 0);
        ld4(g, rowoff * 8 + 4, bf, gv + 4);
        ld4(g, rowoff * 8 + 8, bf, gv + 8);
        ld4(g, rowoff * 8 + 12, bf, gv + 12);

        float s0 = 0.0f, s1 = 0.0f, d0 = 0.0f, d1 = 0.0f;
        #pragma unroll
        for (int k = 0; k < 8; ++k) {
            const float l0 = fmaxf(lg[i][0][k] + b2s_f[k], 0.f);
            const float l1 = fmaxf(lg[i][1][k] + b2s_f[k], 0.f);
            const float e0 = __expf(l0 + gv[k]);
            const float e1 = __expf(l1 + gv[8 + k]);
            s0 += e0; s1 += e1;
            const ushort2 dv = *(const ushort2*)&Dm[((long)k << 20) + rowoff];
            d0 += bf2f(dv.x) * e0;
            d1 += bf2f(dv.y) * e1;
        }

        if (bf) {
            USH* o = (USH*)out;
            *(ushort2*)&o[rowoff] = *(const ushort2*)&((const USH*)Ind)[rowoff];
            *(ushort2*)&o[1048576 + rowoff] = *(const ushort2*)&((const USH*)Loc)[rowoff];
            ushort2 o2; o2.x = f2bf(amk[i][0]); o2.y = f2bf(amk[i][1]);
            *(ushort2*)&o[2 * 1048576 + rowoff] = o2;
            ushort2 o3; o3.x = f2bf(d0 / s0); o3.y = f2bf(d1 / s1);
            *(ushort2*)&o[3 * 1048576 + rowoff] = o3;
        } else {
            float* o = (float*)out;
            *(float2*)&o[rowoff] = *(const float2*)&((const float*)Ind)[rowoff];
            *(float2*)&o[1048576 + rowoff] = *(const float2*)&((const float*)Loc)[rowoff];
            float2 o2; o2.x = amk[i][0]; o2.y = amk[i][1];
            *(float2*)&o[2 * 1048576 + rowoff] = o2;
            float2 o3; o3.x = d0 / s0; o3.y = d1 / s1;
            *(float2*)&o[3 * 1048576 + rowoff] = o3;
        }
    }
}

extern "C" void kernel_launch(void* const* d_in, const int* in_sizes, int n_in,
                              void* d_out, int out_size, void* d_ws, size_t ws_size,
                              hipStream_t stream) {
    const void* x   = d_in[0];
    const void* Ind = d_in[1];
    const void* Loc = d_in[2];
    const void* a   = d_in[3];
    const void* W1m = d_in[4];
    const void* b1m = d_in[5];
    const void* W2m = d_in[6];
    const void* b2m = d_in[7];
    const void* W1s = d_in[8];
    const void* b1s = d_in[9];
    const void* W2s = d_in[10];
    const void* b2s = d_in[11];
    const void* E   = d_in[12];
    const void* g   = d_in[13];

    UIN* ws   = (UIN*)d_ws;
    UIN* hA16 = ws;                    // [9][32][1024] u32, 1.125 MB
    UIN* hB16 = hA16 + 294912;         // 1.125 MB
    USH* Dm   = (USH*)(hB16 + 294912); // [8][1024][1024] bf16, 16 MB

    k_pre_d<<<dim3(800), 256, 0, stream>>>(x, W1m, b1m, W1s, b1s, E, Ind,
                                           hA16, hB16, Dm);
    k_main<<<dim3(32, 32), 256, 0, stream>>>(hA16, hB16, Dm,
                                             Ind, Loc, a, W2m, b2m, W2s, b2s,
                                             g, d_out);
}